// Round 11
// baseline (151.905 us; speedup 1.0000x reference)
//
#include <hip/hip_runtime.h>
#include <hip/hip_bf16.h>
#include <math.h>

#define BQ 2
#define NV 6
#define CIN 64
#define HF 32
#define WF 56
#define ND 32
#define BEVC 128
#define BEVH 128
#define BEVW 128
#define NPIX (HF*WF)     // 1792
#define BV (BQ*NV)       // 12
#define NCOL (BV*WF)     // 672
#define NITEM (NCOL*ND)  // 21504
#define NCELL (BQ*BEVH*BEVW) // 32768
#define EXT 20.0f
#define BN_S 0.99999500003749937f

typedef short bf16x8 __attribute__((ext_vector_type(8)));
typedef float f32x4 __attribute__((ext_vector_type(4)));

__device__ __forceinline__ float gelu(float x) {
    return 0.5f * x * (1.0f + erff(x * 0.70710678118654752f));
}

__device__ __forceinline__ unsigned short f2bf(float x) {
    union { float f; unsigned u; } v; v.f = x;
    unsigned r = v.u + 0x7FFFu + ((v.u >> 16) & 1u);
    return (unsigned short)(r >> 16);
}

// bf16 atomic add via 32-bit CAS (cold fallback path only)
__device__ void atomicAddBf16(unsigned short* addr, float val) {
    unsigned* base = (unsigned*)((size_t)addr & ~(size_t)3);
    bool hi = ((size_t)addr & 2) != 0;
    unsigned old = *base, assumed;
    do {
        assumed = old;
        unsigned short cur = hi ? (unsigned short)(assumed >> 16)
                                : (unsigned short)(assumed & 0xFFFF);
        union { unsigned u; float f; } vv; vv.u = ((unsigned)cur) << 16;
        unsigned short nb = f2bf(vv.f + val);
        unsigned newv = hi ? ((assumed & 0x0000FFFFu) | ((unsigned)nb << 16))
                           : ((assumed & 0xFFFF0000u) | (unsigned)nb);
        old = atomicCAS(base, assumed, newv);
    } while (old != assumed);
}

// ---------------- combined weight prep + count zeroing ----------------
#define WF1_N (9*4*8*64*8)
#define WFP_N (2*8*64*8)
#define WFC1_N (9*2*4*64*8)
__global__ void k_wprep_all(const float* __restrict__ br_w1, const float* __restrict__ br_w2,
                            const float* __restrict__ fp_w, const float* __restrict__ dh_w1,
                            unsigned short* __restrict__ wf1, unsigned short* __restrict__ wf2,
                            unsigned short* __restrict__ wfp, unsigned short* __restrict__ wfc1,
                            int* __restrict__ count) {
    int gi = blockIdx.x * 256 + threadIdx.x;
    if (gi < NCELL) count[gi] = 0;

    int i = gi;
    if (i < 2 * WF1_N) {
        const float* w = (i < WF1_N) ? br_w1 : br_w2;
        unsigned short* wf = (i < WF1_N) ? wf1 : wf2;
        int j = (i < WF1_N) ? i : i - WF1_N;
        int e     = j & 7;
        int lane  = (j >> 3) & 63;
        int ntile = (j >> 9) & 7;
        int kstep = (j >> 12) & 3;
        int kpos  = j >> 14;
        int co = ntile * 16 + (lane & 15);
        int ci = kstep * 32 + ((lane >> 4) << 3) + e;
        wf[j] = f2bf(w[((size_t)co * BEVC + ci) * 9 + kpos]);
        return;
    }
    i -= 2 * WF1_N;
    if (i < WFP_N) {
        int e     = i & 7;
        int lane  = (i >> 3) & 63;
        int ntile = (i >> 9) & 7;
        int kstep = (i >> 12) & 1;
        int co = ntile * 16 + (lane & 15);
        int ci = kstep * 32 + ((lane >> 4) << 3) + e;
        wfp[i] = f2bf(fp_w[(size_t)co * CIN + ci]);
        return;
    }
    i -= WFP_N;
    if (i < WFC1_N) {
        int e     = i & 7;
        int lane  = (i >> 3) & 63;
        int ntile = (i >> 9) & 3;
        int kstep = (i >> 11) & 1;
        int kpos  = i >> 12;
        int co = ntile * 16 + (lane & 15);
        int ci = kstep * 32 + ((lane >> 4) << 3) + e;
        wfc1[i] = f2bf(dh_w1[((size_t)co * CIN + ci) * 9 + kpos]);
    }
}

// ---------------- Kernel 1: fused conv1(MFMA) + depth head + softmax ----------------
#define C1_HW 18
#define C1_HP (C1_HW*6)   // 108 halo pixels
__global__ void k_conv1d(const float* __restrict__ fm, const unsigned short* __restrict__ wfrag,
                         const float* __restrict__ bias, const float* __restrict__ w2,
                         const float* __restrict__ b2, float* __restrict__ dp) {
    __shared__ float hbuf[64 * 65];        // phase A: als halo (char alias); phase B: h tile
    __shared__ float wl2[ND * 65];
    __shared__ float bl2[ND];
    char* als = (char*)hbuf;

    int x0 = blockIdx.x * 16;
    int y0 = blockIdx.y * 4;
    int bv = blockIdx.z;
    const float* fmb = fm + (size_t)bv * CIN * NPIX;

    for (int i = threadIdx.x; i < ND * CIN; i += 256) {
        int d = i >> 6, ci = i & 63;
        wl2[d * 65 + ci] = w2[i];
    }
    if (threadIdx.x < ND) bl2[threadIdx.x] = b2[threadIdx.x];

    for (int i = threadIdx.x; i < C1_HP * 8; i += 256) {
        int pix = i >> 3, oct = i & 7;
        int r = pix / C1_HW, c = pix % C1_HW;
        int gy = y0 + r - 1, gx = x0 + c - 1;
        int4 w4 = {0, 0, 0, 0};
        if ((unsigned)gy < (unsigned)HF && (unsigned)gx < (unsigned)WF) {
            const float* p = fmb + (size_t)(oct * 8) * NPIX + gy * WF + gx;
            unsigned short b8[8];
            #pragma unroll
            for (int j = 0; j < 8; j++) b8[j] = f2bf(p[(size_t)j * NPIX]);
            w4.x = b8[0] | ((int)b8[1] << 16);
            w4.y = b8[2] | ((int)b8[3] << 16);
            w4.z = b8[4] | ((int)b8[5] << 16);
            w4.w = b8[6] | ((int)b8[7] << 16);
        }
        *(int4*)(als + pix * 128 + ((oct * 16) ^ ((pix & 7) << 4))) = w4;
    }
    __syncthreads();

    int wave = threadIdx.x >> 6;
    int lane = threadIdx.x & 63;
    int xx   = lane & 15;
    int kgrp = lane >> 4;

    const bf16x8* wv = (const bf16x8*)wfrag;
    float bi = bias[wave * 16 + xx];
    f32x4 acc[4];
    #pragma unroll
    for (int m = 0; m < 4; m++) acc[m] = (f32x4){bi, bi, bi, bi};

    for (int kpos = 0; kpos < 9; kpos++) {
        int dy = kpos / 3, dx = kpos % 3;
        #pragma unroll
        for (int kstep = 0; kstep < 2; kstep++) {
            bf16x8 b = wv[((kpos * 2 + kstep) * 4 + wave) * 64 + lane];
            #pragma unroll
            for (int m = 0; m < 4; m++) {
                int pix = (m + dy) * C1_HW + xx + dx;
                bf16x8 a = *(const bf16x8*)(als + pix * 128 +
                                            ((kstep * 64 + kgrp * 16) ^ ((pix & 7) << 4)));
                acc[m] = __builtin_amdgcn_mfma_f32_16x16x32_bf16(a, b, acc[m], 0, 0, 0);
            }
        }
    }
    __syncthreads();

    #pragma unroll
    for (int m = 0; m < 4; m++) {
        #pragma unroll
        for (int r = 0; r < 4; r++) {
            int pixel = m * 16 + kgrp * 4 + r;
            hbuf[pixel * 65 + wave * 16 + xx] = gelu(acc[m][r] * BN_S);
        }
    }
    __syncthreads();

    {
        int pixel = threadIdx.x >> 2;
        int part  = threadIdx.x & 3;
        int m = pixel >> 4, xcol = pixel & 15;
        int gy = y0 + m, gx = x0 + xcol;

        float hv[CIN];
        #pragma unroll
        for (int c4 = 0; c4 < CIN / 4; c4++) {
            float4 v = *(const float4*)&hbuf[pixel * 65 + c4 * 4];
            hv[c4 * 4 + 0] = v.x; hv[c4 * 4 + 1] = v.y;
            hv[c4 * 4 + 2] = v.z; hv[c4 * 4 + 3] = v.w;
        }
        float o[8];
        float mx = -1e30f;
        #pragma unroll
        for (int dd = 0; dd < 8; dd++) {
            int d = part * 8 + dd;
            float a = bl2[d];
            #pragma unroll
            for (int ci = 0; ci < CIN; ci++) a += wl2[d * 65 + ci] * hv[ci];
            o[dd] = a;
            mx = fmaxf(mx, a);
        }
        mx = fmaxf(mx, __shfl_xor(mx, 1));
        mx = fmaxf(mx, __shfl_xor(mx, 2));
        float s = 0.f;
        #pragma unroll
        for (int dd = 0; dd < 8; dd++) { o[dd] = expf(o[dd] - mx); s += o[dd]; }
        s += __shfl_xor(s, 1);
        s += __shfl_xor(s, 2);
        float inv = 1.0f / s;
        if (gx < WF) {
            float* op = dp + ((size_t)bv * NPIX + gy * WF + gx) * ND + part * 8;
            float4 v0 = {o[0] * inv, o[1] * inv, o[2] * inv, o[3] * inv};
            float4 v1 = {o[4] * inv, o[5] * inv, o[6] * inv, o[7] * inv};
            ((float4*)op)[0] = v0;
            ((float4*)op)[1] = v1;
        }
    }
}

// ---------------- Kernel 3: 1x1 conv 64->128 via MFMA bf16. out [pix][co] ----------------
__global__ void k_fp(const float* __restrict__ fm, const unsigned short* __restrict__ wfrag,
                     const float* __restrict__ bias, float* __restrict__ fp) {
    __shared__ char als[64 * 128];
    int p0 = blockIdx.x * 64;
    int bv = p0 / NPIX, pl0 = p0 % NPIX;
    const float* fmb = fm + (size_t)bv * CIN * NPIX + pl0;

    #pragma unroll
    for (int it = 0; it < 2; it++) {
        int t = threadIdx.x + it * 256;
        int oct = t >> 6, pix = t & 63;
        unsigned short b8[8];
        #pragma unroll
        for (int j = 0; j < 8; j++)
            b8[j] = f2bf(fmb[(size_t)(oct * 8 + j) * NPIX + pix]);
        int4 w4;
        w4.x = b8[0] | ((int)b8[1] << 16);
        w4.y = b8[2] | ((int)b8[3] << 16);
        w4.z = b8[4] | ((int)b8[5] << 16);
        w4.w = b8[6] | ((int)b8[7] << 16);
        *(int4*)(als + pix * 128 + ((oct * 16) ^ ((pix & 7) << 4))) = w4;
    }
    __syncthreads();

    int wave = threadIdx.x >> 6;
    int lane = threadIdx.x & 63;
    int xx   = lane & 15;
    int kgrp = lane >> 4;

    int prow = wave * 16 + xx;
    bf16x8 a0 = *(const bf16x8*)(als + prow * 128 + ((       kgrp * 16) ^ ((prow & 7) << 4)));
    bf16x8 a1 = *(const bf16x8*)(als + prow * 128 + ((64  +  kgrp * 16) ^ ((prow & 7) << 4)));

    const bf16x8* wv = (const bf16x8*)wfrag;

    #pragma unroll
    for (int n = 0; n < 8; n++) {
        float bi = bias[n * 16 + xx];
        f32x4 acc = (f32x4){bi, bi, bi, bi};
        bf16x8 b0 = wv[(0 * 8 + n) * 64 + lane];
        bf16x8 b1 = wv[(1 * 8 + n) * 64 + lane];
        acc = __builtin_amdgcn_mfma_f32_16x16x32_bf16(a0, b0, acc, 0, 0, 0);
        acc = __builtin_amdgcn_mfma_f32_16x16x32_bf16(a1, b1, acc, 0, 0, 0);
        #pragma unroll
        for (int r = 0; r < 4; r++) {
            int pixel = wave * 16 + kgrp * 4 + r;
            fp[(size_t)(p0 + pixel) * BEVC + n * 16 + xx] = gelu(acc[r] * BN_S);
        }
    }
}

// ---------------- geometry helper ----------------
struct Geo {
    float i00,i01,i02,i10,i11,i12,i20,i21,i22;
    float R00,R01,R02,t0,R10,R11,R12,t1;
};
__device__ __forceinline__ Geo load_geo(const float* Km, const float* Tm, int bv) {
    Geo G;
    const float* Kp = Km + bv * 9;
    float a = Kp[0], bb = Kp[1], cc = Kp[2];
    float d = Kp[3], e  = Kp[4], f  = Kp[5];
    float g = Kp[6], hh = Kp[7], ii = Kp[8];
    float A  = e * ii - f * hh;
    float Bm = -(d * ii - f * g);
    float Cm = d * hh - e * g;
    float det = a * A + bb * Bm + cc * Cm;
    float invd = 1.0f / det;
    G.i00 = A * invd;  G.i01 = -(bb * ii - cc * hh) * invd; G.i02 = (bb * f - cc * e) * invd;
    G.i10 = Bm * invd; G.i11 = (a * ii - cc * g) * invd;    G.i12 = -(a * f - cc * d) * invd;
    G.i20 = Cm * invd; G.i21 = -(a * hh - bb * g) * invd;   G.i22 = (a * e - bb * d) * invd;
    const float* Tp = Tm + bv * 16;
    G.R00 = Tp[0]; G.R01 = Tp[1]; G.R02 = Tp[2]; G.t0 = Tp[3];
    G.R10 = Tp[4]; G.R11 = Tp[5]; G.R12 = Tp[6]; G.t1 = Tp[7];
    return G;
}
__device__ __forceinline__ int geo_cell(const Geo& G, int px, int py, float dep) {
    float fx = (float)px, fy = (float)py;
    float r0 = G.i00 * fx + G.i01 * fy + G.i02;
    float r1 = G.i10 * fx + G.i11 * fy + G.i12;
    float r2 = G.i20 * fx + G.i21 * fy + G.i22;
    float xe = G.R00 * (r0 * dep) + G.R01 * (r1 * dep) + G.R02 * (r2 * dep) + G.t0;
    float ye = G.R10 * (r0 * dep) + G.R11 * (r1 * dep) + G.R12 * (r2 * dep) + G.t1;
    int col = (int)((xe + EXT) / (2.0f * EXT) * (float)(BEVW - 1));
    int row = (int)((ye + EXT) / (2.0f * EXT) * (float)(BEVH - 1));
    return (col >= 0 && col < BEVW && row >= 0 && row < BEVH) ? row * BEVW + col : -1;
}

// ---------------- Kernel 4a: per-column py-pre-reduction + histogram ----------------
__global__ void k_prered(const float* __restrict__ fp, const float* __restrict__ dp,
                         const float* __restrict__ Km, const float* __restrict__ Tm,
                         const float* __restrict__ trust, const float* __restrict__ depths,
                         float* __restrict__ M, int* __restrict__ cellidx,
                         int* __restrict__ count) {
    __shared__ float fpl[HF * BEVC];
    __shared__ float dpl[HF * ND];
    __shared__ int   celll[ND * HF];
    __shared__ int   uni[ND];

    int col = blockIdx.x;
    int bv = col / WF, px = col % WF;
    int b  = bv / NV;
    float tw = trust[bv];

    for (int i = threadIdx.x; i < HF * (BEVC / 4); i += 256) {
        int py = i >> 5, c4 = i & 31;
        float4 v = ((const float4*)(fp + ((size_t)bv * NPIX + py * WF + px) * BEVC))[c4];
        v.x *= tw; v.y *= tw; v.z *= tw; v.w *= tw;
        ((float4*)fpl)[py * 32 + c4] = v;
    }
    for (int i = threadIdx.x; i < HF * (ND / 4); i += 256) {
        int py = i >> 3, d4 = i & 7;
        ((float4*)dpl)[py * 8 + d4] =
            ((const float4*)(dp + ((size_t)bv * NPIX + py * WF + px) * ND))[d4];
    }

    Geo G = load_geo(Km, Tm, bv);
    for (int q = threadIdx.x; q < ND * HF; q += 256) {
        int di = q >> 5, py = q & 31;
        celll[q] = geo_cell(G, px, py, depths[di]);
    }
    __syncthreads();

    if (threadIdx.x < ND) {
        int di = threadIdx.x;
        int c0 = celll[di * HF];
        bool u = true;
        for (int py = 1; py < HF; py++) u &= (celll[di * HF + py] == c0);
        uni[di] = u ? c0 : -2;
    }
    __syncthreads();

    int c = threadIdx.x & 127, dg = threadIdx.x >> 7;
    float acc[16];
    #pragma unroll
    for (int k = 0; k < 16; k++) acc[k] = 0.f;
    for (int py = 0; py < HF; py++) {
        float fv = fpl[py * BEVC + c];
        #pragma unroll
        for (int k = 0; k < 16; k++)
            acc[k] += fv * dpl[py * ND + dg * 16 + k];
    }
    #pragma unroll
    for (int k = 0; k < 16; k++)
        M[((size_t)col * ND + dg * 16 + k) * BEVC + c] = acc[k];

    if (threadIdx.x < ND) {
        int u = uni[threadIdx.x];
        int id = (u >= 0) ? (b * (BEVH * BEVW) + u) : u;
        cellidx[col * ND + threadIdx.x] = id;
        if (id >= 0) atomicAdd(&count[id], 1);
    }
}

// ---------------- Kernel 4c/d: scan + fill ----------------
__global__ void k_scan(const int* __restrict__ count, int* __restrict__ offs,
                       int* __restrict__ cursor) {
    __shared__ int part[1024];
    int t = threadIdx.x;
    int base = t * 32;
    int loc[32];
    int s = 0;
    #pragma unroll
    for (int i = 0; i < 32; i++) { loc[i] = s; s += count[base + i]; }
    part[t] = s;
    __syncthreads();
    for (int off = 1; off < 1024; off <<= 1) {
        int v = (t >= off) ? part[t - off] : 0;
        __syncthreads();
        part[t] += v;
        __syncthreads();
    }
    int pre = (t == 0) ? 0 : part[t - 1];
    #pragma unroll
    for (int i = 0; i < 32; i++) {
        offs[base + i] = pre + loc[i];
        cursor[base + i] = pre + loc[i];
    }
    if (t == 1023) offs[NCELL] = pre + s;
}

__global__ void k_fill(const int* __restrict__ cellidx, int* __restrict__ cursor,
                       int* __restrict__ itemlist) {
    int i = blockIdx.x * 256 + threadIdx.x;
    if (i >= NITEM) return;
    int c = cellidx[i];
    if (c >= 0) {
        int p = atomicAdd(&cursor[c], 1);
        itemlist[p] = i;
    }
}

// ---------------- Kernel 4e: gather -> bf16 bev ----------------
__global__ void k_gather(const float* __restrict__ M, const int* __restrict__ offs,
                         const int* __restrict__ itemlist, unsigned short* __restrict__ bev) {
    int cell = blockIdx.x;
    int s = offs[cell], e = offs[cell + 1];
    int c = threadIdx.x;
    float acc = 0.f;
    for (int j = s; j < e; j++) {
        int it = itemlist[j];
        acc += M[(size_t)it * BEVC + c];
    }
    bev[(size_t)cell * BEVC + c] = f2bf(acc);
}

// ---------------- Kernel 4f: generic fallback (normally no-op) ----------------
__global__ void k_fallback(const float* __restrict__ fp, const float* __restrict__ dp,
                           const float* __restrict__ Km, const float* __restrict__ Tm,
                           const float* __restrict__ trust, const float* __restrict__ depths,
                           const int* __restrict__ cellidx, unsigned short* __restrict__ bev) {
    int col = blockIdx.x;
    bool any = false;
    for (int di = 0; di < ND; di++) any |= (cellidx[col * ND + di] == -2);
    if (!any) return;

    int bv = col / WF, px = col % WF;
    int b  = bv / NV;
    float tw = trust[bv];
    Geo G = load_geo(Km, Tm, bv);
    int c = threadIdx.x;
    unsigned short* bevb = bev + (size_t)b * BEVH * BEVW * BEVC;
    for (int di = 0; di < ND; di++) {
        if (cellidx[col * ND + di] != -2) continue;
        float dep = depths[di];
        for (int py = 0; py < HF; py++) {
            int cell = geo_cell(G, px, py, dep);
            if (cell >= 0) {
                float v = fp[((size_t)bv * NPIX + py * WF + px) * BEVC + c] * tw *
                          dp[((size_t)bv * NPIX + py * WF + px) * ND + di];
                atomicAddBf16(&bevb[(size_t)cell * BEVC + c], v);
            }
        }
    }
}

// ---------------- Kernel 5/6: 3x3 conv 128->128 via MFMA bf16, bf16 in ----------------
// TO_MODE: 1 = bf16 NHWC, 2 = fp32 NCHW (final output, fused transpose). XCD-chunked grid.
#define TX2 16
#define TY2 4
#define HALO_W 18
#define HP (HALO_W*6)   // 108

__device__ __forceinline__ int swz(int pix, int off) {
    return pix * 256 + (off ^ ((pix & 7) << 4));
}

template<int TO_MODE>
__global__ void k_bevconv(const unsigned short* __restrict__ in_,
                          const unsigned short* __restrict__ wfrag,
                          const float* __restrict__ bias, void* __restrict__ out_) {
    __shared__ char ldsb[HP * 256];   // phase A: halo; phase B: output tile
    // XCD-chunked swizzle: 512 blocks, XCD k gets contiguous ids [k*64, k*64+64)
    int bid = blockIdx.x;
    int id = (bid & 7) * 64 + (bid >> 3);
    int x0 = (id & 7) * TX2;
    int y0 = ((id >> 3) & 31) * TY2;
    int b  = id >> 8;

    for (int t = threadIdx.x; t < HP * 16; t += 256) {
        int pix = t >> 4, oct = t & 15;
        int r = pix / HALO_W, c = pix % HALO_W;
        int gy = y0 + r - 1, gx = x0 + c - 1;
        int4 w4 = {0, 0, 0, 0};
        if ((unsigned)gy < (unsigned)BEVH && (unsigned)gx < (unsigned)BEVW)
            w4 = *(const int4*)(in_ + ((size_t)(b * BEVH + gy) * BEVW + gx) * BEVC + oct * 8);
        *(int4*)(ldsb + swz(pix, oct * 16)) = w4;
    }
    __syncthreads();

    int wave = threadIdx.x >> 6;
    int lane = threadIdx.x & 63;
    int xx   = lane & 15;
    int kgrp = lane >> 4;

    const bf16x8* wv = (const bf16x8*)wfrag;

    f32x4 acc[TY2][2];
    {
        float b0 = bias[wave * 32 + xx];
        float b1 = bias[wave * 32 + 16 + xx];
        #pragma unroll
        for (int m = 0; m < TY2; m++) {
            acc[m][0] = (f32x4){b0, b0, b0, b0};
            acc[m][1] = (f32x4){b1, b1, b1, b1};
        }
    }

    for (int kpos = 0; kpos < 9; kpos++) {
        int dy = kpos / 3, dx = kpos % 3;
        #pragma unroll
        for (int kstep = 0; kstep < 4; kstep++) {
            bf16x8 bf0 = wv[((kpos * 4 + kstep) * 8 + wave * 2 + 0) * 64 + lane];
            bf16x8 bf1 = wv[((kpos * 4 + kstep) * 8 + wave * 2 + 1) * 64 + lane];
            #pragma unroll
            for (int m = 0; m < TY2; m++) {
                bf16x8 a = *(const bf16x8*)(ldsb + swz((m + dy) * HALO_W + xx + dx,
                                                       kstep * 64 + kgrp * 16));
                acc[m][0] = __builtin_amdgcn_mfma_f32_16x16x32_bf16(a, bf0, acc[m][0], 0, 0, 0);
                acc[m][1] = __builtin_amdgcn_mfma_f32_16x16x32_bf16(a, bf1, acc[m][1], 0, 0, 0);
            }
        }
    }
    __syncthreads();   // halo reads done; reuse LDS for output tile

    if (TO_MODE == 1) {
        // bf16 NHWC: LDS transpose -> full-line int4 stores
        unsigned short* hl = (unsigned short*)ldsb;  // [64][136] padded
        #pragma unroll
        for (int m = 0; m < TY2; m++)
            #pragma unroll
            for (int n = 0; n < 2; n++)
                #pragma unroll
                for (int r = 0; r < 4; r++) {
                    int pid = m * 16 + kgrp * 4 + r;
                    hl[pid * 136 + wave * 32 + n * 16 + xx] = f2bf(gelu(acc[m][n][r] * BN_S));
                }
        __syncthreads();
        for (int t = threadIdx.x; t < 1024; t += 256) {
            int pid = t >> 4, oct = t & 15;
            int gy = y0 + (pid >> 4), gx = x0 + (pid & 15);
            *(int4*)((unsigned short*)out_ + ((size_t)(b * BEVH + gy) * BEVW + gx) * BEVC + oct * 8) =
                *(int4*)(hl + pid * 136 + oct * 8);
        }
    } else {
        // fp32 NCHW: two co-halves via LDS, 64B float4 runs
        float* fl = (float*)ldsb;   // [64][66] floats
        #pragma unroll
        for (int half = 0; half < 2; half++) {
            if (half == 1) __syncthreads();
            if ((wave >> 1) == half) {
                #pragma unroll
                for (int m = 0; m < TY2; m++)
                    #pragma unroll
                    for (int n = 0; n < 2; n++)
                        #pragma unroll
                        for (int r = 0; r < 4; r++) {
                            int pid = m * 16 + kgrp * 4 + r;
                            fl[pid * 66 + (wave & 1) * 32 + n * 16 + xx] =
                                gelu(acc[m][n][r] * BN_S);
                        }
            }
            __syncthreads();
            for (int t = threadIdx.x; t < 1024; t += 256) {
                int l4 = t & 3, gyl = (t >> 2) & 3, col = t >> 4;
                int co = half * 64 + col;
                int gy = y0 + gyl;
                float4 v;
                v.x = fl[(gyl * 16 + l4 * 4 + 0) * 66 + col];
                v.y = fl[(gyl * 16 + l4 * 4 + 1) * 66 + col];
                v.z = fl[(gyl * 16 + l4 * 4 + 2) * 66 + col];
                v.w = fl[(gyl * 16 + l4 * 4 + 3) * 66 + col];
                *(float4*)((float*)out_ + (((size_t)b * BEVC + co) * BEVH + gy) * BEVW +
                           x0 + l4 * 4) = v;
            }
        }
    }
}

extern "C" void kernel_launch(void* const* d_in, const int* in_sizes, int n_in,
                              void* d_out, int out_size, void* d_ws, size_t ws_size,
                              hipStream_t stream) {
    const float* feat_maps = (const float*)d_in[0];
    const float* Km        = (const float*)d_in[1];
    const float* Tm        = (const float*)d_in[2];
    const float* trust     = (const float*)d_in[3];
    const float* depths    = (const float*)d_in[4];
    const float* dh_w1     = (const float*)d_in[5];
    const float* dh_b1     = (const float*)d_in[6];
    const float* dh_w2     = (const float*)d_in[7];
    const float* dh_b2     = (const float*)d_in[8];
    const float* fp_w      = (const float*)d_in[9];
    const float* fp_b      = (const float*)d_in[10];
    const float* br_w1     = (const float*)d_in[11];
    const float* br_b1     = (const float*)d_in[12];
    const float* br_w2     = (const float*)d_in[13];
    const float* br_b2     = (const float*)d_in[14];
    float* out = (float*)d_out;

    float* ws  = (float*)d_ws;
    float* dpb = ws;                                     // 12*1792*32 f
    float* fpb = dpb + (size_t)BV * NPIX * ND;           // 12*1792*128 f
    float* Mb  = fpb + (size_t)BV * NPIX * BEVC;         // 21504*128 f
    unsigned short* bevb = (unsigned short*)(Mb + (size_t)NITEM * BEVC); // NCELL*128 bf16
    unsigned short* h2b  = bevb + (size_t)NCELL * BEVC;                  // NCELL*128 bf16
    unsigned short* wf1  = h2b + (size_t)NCELL * BEVC;
    unsigned short* wf2  = wf1 + (size_t)WF1_N;
    unsigned short* wfp  = wf2 + (size_t)WF1_N;
    unsigned short* wfc1 = wfp + WFP_N;
    int* cellidx  = (int*)(wfc1 + WFC1_N);  // NITEM
    int* count    = cellidx + NITEM;        // NCELL
    int* offs     = count + NCELL;          // NCELL+1
    int* cursor   = offs + NCELL + 1;       // NCELL
    int* itemlist = cursor + NCELL;         // NITEM

    // combined weight prep + count zeroing
    {
        int total = 2 * WF1_N + WFP_N + WFC1_N;
        k_wprep_all<<<dim3((total + 255) / 256), dim3(256), 0, stream>>>(
            br_w1, br_w2, fp_w, dh_w1, wf1, wf2, wfp, wfc1, count);
    }

    // fused conv1 + depth head + softmax
    k_conv1d<<<dim3(4, HF / 4, BV), dim3(256), 0, stream>>>(
        feat_maps, wfc1, dh_b1, dh_w2, dh_b2, dpb);

    // feature projection (MFMA)
    k_fp<<<dim3(BV * NPIX / 64), dim3(256), 0, stream>>>(feat_maps, wfp, fp_b, fpb);

    // --- scatter via sort+gather (no fp32 atomics) ---
    k_prered<<<dim3(NCOL), dim3(256), 0, stream>>>(fpb, dpb, Km, Tm, trust, depths,
                                                   Mb, cellidx, count);
    k_scan<<<dim3(1), dim3(1024), 0, stream>>>(count, offs, cursor);
    k_fill<<<dim3((NITEM + 255) / 256), dim3(256), 0, stream>>>(cellidx, cursor, itemlist);
    k_gather<<<dim3(NCELL), dim3(BEVC), 0, stream>>>(Mb, offs, itemlist, bevb);
    k_fallback<<<dim3(NCOL), dim3(BEVC), 0, stream>>>(fpb, dpb, Km, Tm, trust, depths,
                                                      cellidx, bevb);

    // BEV refinement convs (MFMA, bf16 in): -> bf16 NHWC, then -> fp32 NCHW (fused transpose)
    k_bevconv<1><<<dim3(512), dim3(256), 0, stream>>>(bevb, wf1, br_b1, h2b);
    k_bevconv<2><<<dim3(512), dim3(256), 0, stream>>>(h2b, wf2, br_b2, out);
}

// Round 12
// 120.443 us; speedup vs baseline: 1.2612x; 1.2612x over previous
//
#include <hip/hip_runtime.h>
#include <hip/hip_bf16.h>
#include <math.h>

#define BQ 2
#define NV 6
#define CIN 64
#define HF 32
#define WF 56
#define ND 32
#define BEVC 128
#define BEVH 128
#define BEVW 128
#define NPIX (HF*WF)     // 1792
#define BV (BQ*NV)       // 12
#define NCOL (BV*WF)     // 672
#define NITEM (NCOL*ND)  // 21504
#define NCELL (BQ*BEVH*BEVW) // 32768
#define EXT 20.0f
#define BN_S 0.99999500003749937f

typedef short bf16x8 __attribute__((ext_vector_type(8)));
typedef float f32x4 __attribute__((ext_vector_type(4)));

__device__ __forceinline__ float gelu(float x) {
    return 0.5f * x * (1.0f + erff(x * 0.70710678118654752f));
}

__device__ __forceinline__ unsigned short f2bf(float x) {
    union { float f; unsigned u; } v; v.f = x;
    unsigned r = v.u + 0x7FFFu + ((v.u >> 16) & 1u);
    return (unsigned short)(r >> 16);
}

// bf16 atomic add via 32-bit CAS (cold fallback path only)
__device__ void atomicAddBf16(unsigned short* addr, float val) {
    unsigned* base = (unsigned*)((size_t)addr & ~(size_t)3);
    bool hi = ((size_t)addr & 2) != 0;
    unsigned old = *base, assumed;
    do {
        assumed = old;
        unsigned short cur = hi ? (unsigned short)(assumed >> 16)
                                : (unsigned short)(assumed & 0xFFFF);
        union { unsigned u; float f; } vv; vv.u = ((unsigned)cur) << 16;
        unsigned short nb = f2bf(vv.f + val);
        unsigned newv = hi ? ((assumed & 0x0000FFFFu) | ((unsigned)nb << 16))
                           : ((assumed & 0xFFFF0000u) | (unsigned)nb);
        old = atomicCAS(base, assumed, newv);
    } while (old != assumed);
}

// ---------------- combined weight prep + count zeroing ----------------
#define WF1_N (9*4*8*64*8)
#define WFP_N (2*8*64*8)
#define WFC1_N (9*2*4*64*8)
__global__ void k_wprep_all(const float* __restrict__ br_w1, const float* __restrict__ br_w2,
                            const float* __restrict__ fp_w, const float* __restrict__ dh_w1,
                            unsigned short* __restrict__ wf1, unsigned short* __restrict__ wf2,
                            unsigned short* __restrict__ wfp, unsigned short* __restrict__ wfc1,
                            int* __restrict__ count) {
    int gi = blockIdx.x * 256 + threadIdx.x;
    if (gi < NCELL) count[gi] = 0;

    int i = gi;
    if (i < 2 * WF1_N) {
        const float* w = (i < WF1_N) ? br_w1 : br_w2;
        unsigned short* wf = (i < WF1_N) ? wf1 : wf2;
        int j = (i < WF1_N) ? i : i - WF1_N;
        int e     = j & 7;
        int lane  = (j >> 3) & 63;
        int ntile = (j >> 9) & 7;
        int kstep = (j >> 12) & 3;
        int kpos  = j >> 14;
        int co = ntile * 16 + (lane & 15);
        int ci = kstep * 32 + ((lane >> 4) << 3) + e;
        wf[j] = f2bf(w[((size_t)co * BEVC + ci) * 9 + kpos]);
        return;
    }
    i -= 2 * WF1_N;
    if (i < WFP_N) {
        int e     = i & 7;
        int lane  = (i >> 3) & 63;
        int ntile = (i >> 9) & 7;
        int kstep = (i >> 12) & 1;
        int co = ntile * 16 + (lane & 15);
        int ci = kstep * 32 + ((lane >> 4) << 3) + e;
        wfp[i] = f2bf(fp_w[(size_t)co * CIN + ci]);
        return;
    }
    i -= WFP_N;
    if (i < WFC1_N) {
        int e     = i & 7;
        int lane  = (i >> 3) & 63;
        int ntile = (i >> 9) & 3;
        int kstep = (i >> 11) & 1;
        int kpos  = i >> 12;
        int co = ntile * 16 + (lane & 15);
        int ci = kstep * 32 + ((lane >> 4) << 3) + e;
        wfc1[i] = f2bf(dh_w1[((size_t)co * CIN + ci) * 9 + kpos]);
    }
}

// ---------------- Kernel 1: fused conv1(MFMA) + depth head + softmax ----------------
#define C1_HW 18
#define C1_HP (C1_HW*6)   // 108 halo pixels
__global__ void k_conv1d(const float* __restrict__ fm, const unsigned short* __restrict__ wfrag,
                         const float* __restrict__ bias, const float* __restrict__ w2,
                         const float* __restrict__ b2, float* __restrict__ dp) {
    __shared__ float hbuf[64 * 65];        // phase A: als halo (char alias); phase B: h tile
    __shared__ float wl2[ND * 65];
    __shared__ float bl2[ND];
    char* als = (char*)hbuf;

    int x0 = blockIdx.x * 16;
    int y0 = blockIdx.y * 4;
    int bv = blockIdx.z;
    const float* fmb = fm + (size_t)bv * CIN * NPIX;

    for (int i = threadIdx.x; i < ND * CIN; i += 256) {
        int d = i >> 6, ci = i & 63;
        wl2[d * 65 + ci] = w2[i];
    }
    if (threadIdx.x < ND) bl2[threadIdx.x] = b2[threadIdx.x];

    for (int i = threadIdx.x; i < C1_HP * 8; i += 256) {
        int pix = i >> 3, oct = i & 7;
        int r = pix / C1_HW, c = pix % C1_HW;
        int gy = y0 + r - 1, gx = x0 + c - 1;
        int4 w4 = {0, 0, 0, 0};
        if ((unsigned)gy < (unsigned)HF && (unsigned)gx < (unsigned)WF) {
            const float* p = fmb + (size_t)(oct * 8) * NPIX + gy * WF + gx;
            unsigned short b8[8];
            #pragma unroll
            for (int j = 0; j < 8; j++) b8[j] = f2bf(p[(size_t)j * NPIX]);
            w4.x = b8[0] | ((int)b8[1] << 16);
            w4.y = b8[2] | ((int)b8[3] << 16);
            w4.z = b8[4] | ((int)b8[5] << 16);
            w4.w = b8[6] | ((int)b8[7] << 16);
        }
        *(int4*)(als + pix * 128 + ((oct * 16) ^ ((pix & 7) << 4))) = w4;
    }
    __syncthreads();

    int wave = threadIdx.x >> 6;
    int lane = threadIdx.x & 63;
    int xx   = lane & 15;
    int kgrp = lane >> 4;

    const bf16x8* wv = (const bf16x8*)wfrag;
    float bi = bias[wave * 16 + xx];
    f32x4 acc[4];
    #pragma unroll
    for (int m = 0; m < 4; m++) acc[m] = (f32x4){bi, bi, bi, bi};

    for (int kpos = 0; kpos < 9; kpos++) {
        int dy = kpos / 3, dx = kpos % 3;
        #pragma unroll
        for (int kstep = 0; kstep < 2; kstep++) {
            bf16x8 b = wv[((kpos * 2 + kstep) * 4 + wave) * 64 + lane];
            #pragma unroll
            for (int m = 0; m < 4; m++) {
                int pix = (m + dy) * C1_HW + xx + dx;
                bf16x8 a = *(const bf16x8*)(als + pix * 128 +
                                            ((kstep * 64 + kgrp * 16) ^ ((pix & 7) << 4)));
                acc[m] = __builtin_amdgcn_mfma_f32_16x16x32_bf16(a, b, acc[m], 0, 0, 0);
            }
        }
    }
    __syncthreads();

    #pragma unroll
    for (int m = 0; m < 4; m++) {
        #pragma unroll
        for (int r = 0; r < 4; r++) {
            int pixel = m * 16 + kgrp * 4 + r;
            hbuf[pixel * 65 + wave * 16 + xx] = gelu(acc[m][r] * BN_S);
        }
    }
    __syncthreads();

    {
        int pixel = threadIdx.x >> 2;
        int part  = threadIdx.x & 3;
        int m = pixel >> 4, xcol = pixel & 15;
        int gy = y0 + m, gx = x0 + xcol;

        float hv[CIN];
        #pragma unroll
        for (int c4 = 0; c4 < CIN / 4; c4++) {
            float4 v = *(const float4*)&hbuf[pixel * 65 + c4 * 4];
            hv[c4 * 4 + 0] = v.x; hv[c4 * 4 + 1] = v.y;
            hv[c4 * 4 + 2] = v.z; hv[c4 * 4 + 3] = v.w;
        }
        float o[8];
        float mx = -1e30f;
        #pragma unroll
        for (int dd = 0; dd < 8; dd++) {
            int d = part * 8 + dd;
            float a = bl2[d];
            #pragma unroll
            for (int ci = 0; ci < CIN; ci++) a += wl2[d * 65 + ci] * hv[ci];
            o[dd] = a;
            mx = fmaxf(mx, a);
        }
        mx = fmaxf(mx, __shfl_xor(mx, 1));
        mx = fmaxf(mx, __shfl_xor(mx, 2));
        float s = 0.f;
        #pragma unroll
        for (int dd = 0; dd < 8; dd++) { o[dd] = expf(o[dd] - mx); s += o[dd]; }
        s += __shfl_xor(s, 1);
        s += __shfl_xor(s, 2);
        float inv = 1.0f / s;
        if (gx < WF) {
            float* op = dp + ((size_t)bv * NPIX + gy * WF + gx) * ND + part * 8;
            float4 v0 = {o[0] * inv, o[1] * inv, o[2] * inv, o[3] * inv};
            float4 v1 = {o[4] * inv, o[5] * inv, o[6] * inv, o[7] * inv};
            ((float4*)op)[0] = v0;
            ((float4*)op)[1] = v1;
        }
    }
}

// ---------------- Kernel 3: 1x1 conv 64->128 via MFMA bf16. out [pix][co] ----------------
__global__ void k_fp(const float* __restrict__ fm, const unsigned short* __restrict__ wfrag,
                     const float* __restrict__ bias, float* __restrict__ fp) {
    __shared__ char als[64 * 128];
    int p0 = blockIdx.x * 64;
    int bv = p0 / NPIX, pl0 = p0 % NPIX;
    const float* fmb = fm + (size_t)bv * CIN * NPIX + pl0;

    #pragma unroll
    for (int it = 0; it < 2; it++) {
        int t = threadIdx.x + it * 256;
        int oct = t >> 6, pix = t & 63;
        unsigned short b8[8];
        #pragma unroll
        for (int j = 0; j < 8; j++)
            b8[j] = f2bf(fmb[(size_t)(oct * 8 + j) * NPIX + pix]);
        int4 w4;
        w4.x = b8[0] | ((int)b8[1] << 16);
        w4.y = b8[2] | ((int)b8[3] << 16);
        w4.z = b8[4] | ((int)b8[5] << 16);
        w4.w = b8[6] | ((int)b8[7] << 16);
        *(int4*)(als + pix * 128 + ((oct * 16) ^ ((pix & 7) << 4))) = w4;
    }
    __syncthreads();

    int wave = threadIdx.x >> 6;
    int lane = threadIdx.x & 63;
    int xx   = lane & 15;
    int kgrp = lane >> 4;

    int prow = wave * 16 + xx;
    bf16x8 a0 = *(const bf16x8*)(als + prow * 128 + ((       kgrp * 16) ^ ((prow & 7) << 4)));
    bf16x8 a1 = *(const bf16x8*)(als + prow * 128 + ((64  +  kgrp * 16) ^ ((prow & 7) << 4)));

    const bf16x8* wv = (const bf16x8*)wfrag;

    #pragma unroll
    for (int n = 0; n < 8; n++) {
        float bi = bias[n * 16 + xx];
        f32x4 acc = (f32x4){bi, bi, bi, bi};
        bf16x8 b0 = wv[(0 * 8 + n) * 64 + lane];
        bf16x8 b1 = wv[(1 * 8 + n) * 64 + lane];
        acc = __builtin_amdgcn_mfma_f32_16x16x32_bf16(a0, b0, acc, 0, 0, 0);
        acc = __builtin_amdgcn_mfma_f32_16x16x32_bf16(a1, b1, acc, 0, 0, 0);
        #pragma unroll
        for (int r = 0; r < 4; r++) {
            int pixel = wave * 16 + kgrp * 4 + r;
            fp[(size_t)(p0 + pixel) * BEVC + n * 16 + xx] = gelu(acc[r] * BN_S);
        }
    }
}

// ---------------- geometry helper ----------------
struct Geo {
    float i00,i01,i02,i10,i11,i12,i20,i21,i22;
    float R00,R01,R02,t0,R10,R11,R12,t1;
};
__device__ __forceinline__ Geo load_geo(const float* Km, const float* Tm, int bv) {
    Geo G;
    const float* Kp = Km + bv * 9;
    float a = Kp[0], bb = Kp[1], cc = Kp[2];
    float d = Kp[3], e  = Kp[4], f  = Kp[5];
    float g = Kp[6], hh = Kp[7], ii = Kp[8];
    float A  = e * ii - f * hh;
    float Bm = -(d * ii - f * g);
    float Cm = d * hh - e * g;
    float det = a * A + bb * Bm + cc * Cm;
    float invd = 1.0f / det;
    G.i00 = A * invd;  G.i01 = -(bb * ii - cc * hh) * invd; G.i02 = (bb * f - cc * e) * invd;
    G.i10 = Bm * invd; G.i11 = (a * ii - cc * g) * invd;    G.i12 = -(a * f - cc * d) * invd;
    G.i20 = Cm * invd; G.i21 = -(a * hh - bb * g) * invd;   G.i22 = (a * e - bb * d) * invd;
    const float* Tp = Tm + bv * 16;
    G.R00 = Tp[0]; G.R01 = Tp[1]; G.R02 = Tp[2]; G.t0 = Tp[3];
    G.R10 = Tp[4]; G.R11 = Tp[5]; G.R12 = Tp[6]; G.t1 = Tp[7];
    return G;
}
__device__ __forceinline__ int geo_cell(const Geo& G, int px, int py, float dep) {
    float fx = (float)px, fy = (float)py;
    float r0 = G.i00 * fx + G.i01 * fy + G.i02;
    float r1 = G.i10 * fx + G.i11 * fy + G.i12;
    float r2 = G.i20 * fx + G.i21 * fy + G.i22;
    float xe = G.R00 * (r0 * dep) + G.R01 * (r1 * dep) + G.R02 * (r2 * dep) + G.t0;
    float ye = G.R10 * (r0 * dep) + G.R11 * (r1 * dep) + G.R12 * (r2 * dep) + G.t1;
    int col = (int)((xe + EXT) / (2.0f * EXT) * (float)(BEVW - 1));
    int row = (int)((ye + EXT) / (2.0f * EXT) * (float)(BEVH - 1));
    return (col >= 0 && col < BEVW && row >= 0 && row < BEVH) ? row * BEVW + col : -1;
}

// ---------------- Kernel 4a: per-column py-pre-reduction + histogram ----------------
__global__ void k_prered(const float* __restrict__ fp, const float* __restrict__ dp,
                         const float* __restrict__ Km, const float* __restrict__ Tm,
                         const float* __restrict__ trust, const float* __restrict__ depths,
                         float* __restrict__ M, int* __restrict__ cellidx,
                         int* __restrict__ count) {
    __shared__ float fpl[HF * BEVC];
    __shared__ float dpl[HF * ND];
    __shared__ int   celll[ND * HF];
    __shared__ int   uni[ND];

    int col = blockIdx.x;
    int bv = col / WF, px = col % WF;
    int b  = bv / NV;
    float tw = trust[bv];

    for (int i = threadIdx.x; i < HF * (BEVC / 4); i += 256) {
        int py = i >> 5, c4 = i & 31;
        float4 v = ((const float4*)(fp + ((size_t)bv * NPIX + py * WF + px) * BEVC))[c4];
        v.x *= tw; v.y *= tw; v.z *= tw; v.w *= tw;
        ((float4*)fpl)[py * 32 + c4] = v;
    }
    for (int i = threadIdx.x; i < HF * (ND / 4); i += 256) {
        int py = i >> 3, d4 = i & 7;
        ((float4*)dpl)[py * 8 + d4] =
            ((const float4*)(dp + ((size_t)bv * NPIX + py * WF + px) * ND))[d4];
    }

    Geo G = load_geo(Km, Tm, bv);
    for (int q = threadIdx.x; q < ND * HF; q += 256) {
        int di = q >> 5, py = q & 31;
        celll[q] = geo_cell(G, px, py, depths[di]);
    }
    __syncthreads();

    if (threadIdx.x < ND) {
        int di = threadIdx.x;
        int c0 = celll[di * HF];
        bool u = true;
        for (int py = 1; py < HF; py++) u &= (celll[di * HF + py] == c0);
        uni[di] = u ? c0 : -2;
    }
    __syncthreads();

    int c = threadIdx.x & 127, dg = threadIdx.x >> 7;
    float acc[16];
    #pragma unroll
    for (int k = 0; k < 16; k++) acc[k] = 0.f;
    for (int py = 0; py < HF; py++) {
        float fv = fpl[py * BEVC + c];
        #pragma unroll
        for (int k = 0; k < 16; k++)
            acc[k] += fv * dpl[py * ND + dg * 16 + k];
    }
    #pragma unroll
    for (int k = 0; k < 16; k++)
        M[((size_t)col * ND + dg * 16 + k) * BEVC + c] = acc[k];

    if (threadIdx.x < ND) {
        int u = uni[threadIdx.x];
        int id = (u >= 0) ? (b * (BEVH * BEVW) + u) : u;
        cellidx[col * ND + threadIdx.x] = id;
        if (id >= 0) atomicAdd(&count[id], 1);
    }
}

// ---------------- Kernel 4c/d: scan + fill ----------------
__global__ void k_scan(const int* __restrict__ count, int* __restrict__ offs,
                       int* __restrict__ cursor) {
    __shared__ int part[1024];
    int t = threadIdx.x;
    int base = t * 32;
    int loc[32];
    int s = 0;
    #pragma unroll
    for (int i = 0; i < 32; i++) { loc[i] = s; s += count[base + i]; }
    part[t] = s;
    __syncthreads();
    for (int off = 1; off < 1024; off <<= 1) {
        int v = (t >= off) ? part[t - off] : 0;
        __syncthreads();
        part[t] += v;
        __syncthreads();
    }
    int pre = (t == 0) ? 0 : part[t - 1];
    #pragma unroll
    for (int i = 0; i < 32; i++) {
        offs[base + i] = pre + loc[i];
        cursor[base + i] = pre + loc[i];
    }
    if (t == 1023) offs[NCELL] = pre + s;
}

__global__ void k_fill(const int* __restrict__ cellidx, int* __restrict__ cursor,
                       int* __restrict__ itemlist) {
    int i = blockIdx.x * 256 + threadIdx.x;
    if (i >= NITEM) return;
    int c = cellidx[i];
    if (c >= 0) {
        int p = atomicAdd(&cursor[c], 1);
        itemlist[p] = i;
    }
}

// ---------------- Kernel 4e: gather -> bf16 bev ----------------
__global__ void k_gather(const float* __restrict__ M, const int* __restrict__ offs,
                         const int* __restrict__ itemlist, unsigned short* __restrict__ bev) {
    int cell = blockIdx.x;
    int s = offs[cell], e = offs[cell + 1];
    int c = threadIdx.x;
    float acc = 0.f;
    for (int j = s; j < e; j++) {
        int it = itemlist[j];
        acc += M[(size_t)it * BEVC + c];
    }
    bev[(size_t)cell * BEVC + c] = f2bf(acc);
}

// ---------------- Kernel 4f: generic fallback (normally no-op) ----------------
__global__ void k_fallback(const float* __restrict__ fp, const float* __restrict__ dp,
                           const float* __restrict__ Km, const float* __restrict__ Tm,
                           const float* __restrict__ trust, const float* __restrict__ depths,
                           const int* __restrict__ cellidx, unsigned short* __restrict__ bev) {
    int col = blockIdx.x;
    bool any = false;
    for (int di = 0; di < ND; di++) any |= (cellidx[col * ND + di] == -2);
    if (!any) return;

    int bv = col / WF, px = col % WF;
    int b  = bv / NV;
    float tw = trust[bv];
    Geo G = load_geo(Km, Tm, bv);
    int c = threadIdx.x;
    unsigned short* bevb = bev + (size_t)b * BEVH * BEVW * BEVC;
    for (int di = 0; di < ND; di++) {
        if (cellidx[col * ND + di] != -2) continue;
        float dep = depths[di];
        for (int py = 0; py < HF; py++) {
            int cell = geo_cell(G, px, py, dep);
            if (cell >= 0) {
                float v = fp[((size_t)bv * NPIX + py * WF + px) * BEVC + c] * tw *
                          dp[((size_t)bv * NPIX + py * WF + px) * ND + di];
                atomicAddBf16(&bevb[(size_t)cell * BEVC + c], v);
            }
        }
    }
}

// ---------------- Kernel 5/6: 3x3 conv 128->128 via MFMA bf16, bf16 in ----------------
// TO_MODE: 1 = bf16 NHWC, 2 = fp32 NCHW (fused transpose). XCD-chunked grid.
// Ring-buffer weight prefetch (depth 4) to break the serial global-load chain.
#define TX2 16
#define TY2 4
#define HALO_W 18
#define HP (HALO_W*6)   // 108

__device__ __forceinline__ int swz(int pix, int off) {
    return pix * 256 + (off ^ ((pix & 7) << 4));
}

template<int TO_MODE>
__global__ __launch_bounds__(256, 2)
void k_bevconv(const unsigned short* __restrict__ in_,
               const unsigned short* __restrict__ wfrag,
               const float* __restrict__ bias, void* __restrict__ out_) {
    __shared__ char ldsb[HP * 256];   // phase A: halo; phase B: output tile
    int bid = blockIdx.x;
    int id = (bid & 7) * 64 + (bid >> 3);
    int x0 = (id & 7) * TX2;
    int y0 = ((id >> 3) & 31) * TY2;
    int b  = id >> 8;

    for (int t = threadIdx.x; t < HP * 16; t += 256) {
        int pix = t >> 4, oct = t & 15;
        int r = pix / HALO_W, c = pix % HALO_W;
        int gy = y0 + r - 1, gx = x0 + c - 1;
        int4 w4 = {0, 0, 0, 0};
        if ((unsigned)gy < (unsigned)BEVH && (unsigned)gx < (unsigned)BEVW)
            w4 = *(const int4*)(in_ + ((size_t)(b * BEVH + gy) * BEVW + gx) * BEVC + oct * 8);
        *(int4*)(ldsb + swz(pix, oct * 16)) = w4;
    }

    int wave = threadIdx.x >> 6;
    int lane = threadIdx.x & 63;
    int xx   = lane & 15;
    int kgrp = lane >> 4;

    const bf16x8* wv = (const bf16x8*)wfrag;
    int wbase = wave * 2;

    // prologue: 4 (kpos,kstep)-pairs of weight frags in flight (issued before barrier)
    bf16x8 wq[4][2];
    #pragma unroll
    for (int p = 0; p < 4; p++) {
        wq[p][0] = wv[(p * 8 + wbase + 0) * 64 + lane];
        wq[p][1] = wv[(p * 8 + wbase + 1) * 64 + lane];
    }

    f32x4 acc[TY2][2];
    {
        float b0 = bias[wave * 32 + xx];
        float b1 = bias[wave * 32 + 16 + xx];
        #pragma unroll
        for (int m = 0; m < TY2; m++) {
            acc[m][0] = (f32x4){b0, b0, b0, b0};
            acc[m][1] = (f32x4){b1, b1, b1, b1};
        }
    }
    __syncthreads();

    #pragma unroll
    for (int i = 0; i < 36; i++) {           // i = kpos*4 + kstep
        const int kpos = i >> 2, kstep = i & 3;
        const int dy = kpos / 3, dx = kpos % 3;
        bf16x8 b0 = wq[i & 3][0];
        bf16x8 b1 = wq[i & 3][1];
        if (i + 4 < 36) {                    // refill slot: pair i+4 (4-deep pipeline)
            wq[i & 3][0] = wv[((i + 4) * 8 + wbase + 0) * 64 + lane];
            wq[i & 3][1] = wv[((i + 4) * 8 + wbase + 1) * 64 + lane];
        }
        #pragma unroll
        for (int m = 0; m < TY2; m++) {
            bf16x8 a = *(const bf16x8*)(ldsb + swz((m + dy) * HALO_W + xx + dx,
                                                   kstep * 64 + kgrp * 16));
            acc[m][0] = __builtin_amdgcn_mfma_f32_16x16x32_bf16(a, b0, acc[m][0], 0, 0, 0);
            acc[m][1] = __builtin_amdgcn_mfma_f32_16x16x32_bf16(a, b1, acc[m][1], 0, 0, 0);
        }
    }
    __syncthreads();   // halo reads done; reuse LDS for output tile

    if (TO_MODE == 1) {
        unsigned short* hl = (unsigned short*)ldsb;  // [64][136] padded
        #pragma unroll
        for (int m = 0; m < TY2; m++)
            #pragma unroll
            for (int n = 0; n < 2; n++)
                #pragma unroll
                for (int r = 0; r < 4; r++) {
                    int pid = m * 16 + kgrp * 4 + r;
                    hl[pid * 136 + wave * 32 + n * 16 + xx] = f2bf(gelu(acc[m][n][r] * BN_S));
                }
        __syncthreads();
        for (int t = threadIdx.x; t < 1024; t += 256) {
            int pid = t >> 4, oct = t & 15;
            int gy = y0 + (pid >> 4), gx = x0 + (pid & 15);
            *(int4*)((unsigned short*)out_ + ((size_t)(b * BEVH + gy) * BEVW + gx) * BEVC + oct * 8) =
                *(int4*)(hl + pid * 136 + oct * 8);
        }
    } else {
        float* fl = (float*)ldsb;   // [64][66] floats
        #pragma unroll
        for (int half = 0; half < 2; half++) {
            if (half == 1) __syncthreads();
            if ((wave >> 1) == half) {
                #pragma unroll
                for (int m = 0; m < TY2; m++)
                    #pragma unroll
                    for (int n = 0; n < 2; n++)
                        #pragma unroll
                        for (int r = 0; r < 4; r++) {
                            int pid = m * 16 + kgrp * 4 + r;
                            fl[pid * 66 + (wave & 1) * 32 + n * 16 + xx] =
                                gelu(acc[m][n][r] * BN_S);
                        }
            }
            __syncthreads();
            for (int t = threadIdx.x; t < 1024; t += 256) {
                int l4 = t & 3, gyl = (t >> 2) & 3, col = t >> 4;
                int co = half * 64 + col;
                int gy = y0 + gyl;
                float4 v;
                v.x = fl[(gyl * 16 + l4 * 4 + 0) * 66 + col];
                v.y = fl[(gyl * 16 + l4 * 4 + 1) * 66 + col];
                v.z = fl[(gyl * 16 + l4 * 4 + 2) * 66 + col];
                v.w = fl[(gyl * 16 + l4 * 4 + 3) * 66 + col];
                *(float4*)((float*)out_ + (((size_t)b * BEVC + co) * BEVH + gy) * BEVW +
                           x0 + l4 * 4) = v;
            }
        }
    }
}

extern "C" void kernel_launch(void* const* d_in, const int* in_sizes, int n_in,
                              void* d_out, int out_size, void* d_ws, size_t ws_size,
                              hipStream_t stream) {
    const float* feat_maps = (const float*)d_in[0];
    const float* Km        = (const float*)d_in[1];
    const float* Tm        = (const float*)d_in[2];
    const float* trust     = (const float*)d_in[3];
    const float* depths    = (const float*)d_in[4];
    const float* dh_w1     = (const float*)d_in[5];
    const float* dh_b1     = (const float*)d_in[6];
    const float* dh_w2     = (const float*)d_in[7];
    const float* dh_b2     = (const float*)d_in[8];
    const float* fp_w      = (const float*)d_in[9];
    const float* fp_b      = (const float*)d_in[10];
    const float* br_w1     = (const float*)d_in[11];
    const float* br_b1     = (const float*)d_in[12];
    const float* br_w2     = (const float*)d_in[13];
    const float* br_b2     = (const float*)d_in[14];
    float* out = (float*)d_out;

    float* ws  = (float*)d_ws;
    float* dpb = ws;                                     // 12*1792*32 f
    float* fpb = dpb + (size_t)BV * NPIX * ND;           // 12*1792*128 f
    float* Mb  = fpb + (size_t)BV * NPIX * BEVC;         // 21504*128 f
    unsigned short* bevb = (unsigned short*)(Mb + (size_t)NITEM * BEVC); // NCELL*128 bf16
    unsigned short* h2b  = bevb + (size_t)NCELL * BEVC;                  // NCELL*128 bf16
    unsigned short* wf1  = h2b + (size_t)NCELL * BEVC;
    unsigned short* wf2  = wf1 + (size_t)WF1_N;
    unsigned short* wfp  = wf2 + (size_t)WF1_N;
    unsigned short* wfc1 = wfp + WFP_N;
    int* cellidx  = (int*)(wfc1 + WFC1_N);  // NITEM
    int* count    = cellidx + NITEM;        // NCELL
    int* offs     = count + NCELL;          // NCELL+1
    int* cursor   = offs + NCELL + 1;       // NCELL
    int* itemlist = cursor + NCELL;         // NITEM

    // combined weight prep + count zeroing
    {
        int total = 2 * WF1_N + WFP_N + WFC1_N;
        k_wprep_all<<<dim3((total + 255) / 256), dim3(256), 0, stream>>>(
            br_w1, br_w2, fp_w, dh_w1, wf1, wf2, wfp, wfc1, count);
    }

    // fused conv1 + depth head + softmax
    k_conv1d<<<dim3(4, HF / 4, BV), dim3(256), 0, stream>>>(
        feat_maps, wfc1, dh_b1, dh_w2, dh_b2, dpb);

    // feature projection (MFMA)
    k_fp<<<dim3(BV * NPIX / 64), dim3(256), 0, stream>>>(feat_maps, wfp, fp_b, fpb);

    // --- scatter via sort+gather (no fp32 atomics) ---
    k_prered<<<dim3(NCOL), dim3(256), 0, stream>>>(fpb, dpb, Km, Tm, trust, depths,
                                                   Mb, cellidx, count);
    k_scan<<<dim3(1), dim3(1024), 0, stream>>>(count, offs, cursor);
    k_fill<<<dim3((NITEM + 255) / 256), dim3(256), 0, stream>>>(cellidx, cursor, itemlist);
    k_gather<<<dim3(NCELL), dim3(BEVC), 0, stream>>>(Mb, offs, itemlist, bevb);
    k_fallback<<<dim3(NCOL), dim3(BEVC), 0, stream>>>(fpb, dpb, Km, Tm, trust, depths,
                                                      cellidx, bevb);

    // BEV refinement convs (MFMA, bf16 in): -> bf16 NHWC, then -> fp32 NCHW (fused transpose)
    k_bevconv<1><<<dim3(512), dim3(256), 0, stream>>>(bevb, wf1, br_b1, h2b);
    k_bevconv<2><<<dim3(512), dim3(256), 0, stream>>>(h2b, wf2, br_b2, out);
}

// Round 13
// 110.871 us; speedup vs baseline: 1.3701x; 1.0863x over previous
//
#include <hip/hip_runtime.h>
#include <hip/hip_bf16.h>
#include <math.h>

#define BQ 2
#define NV 6
#define CIN 64
#define HF 32
#define WF 56
#define ND 32
#define BEVC 128
#define BEVH 128
#define BEVW 128
#define NPIX (HF*WF)     // 1792
#define BV (BQ*NV)       // 12
#define NCOL (BV*WF)     // 672
#define NITEM (NCOL*ND)  // 21504
#define NCELL (BQ*BEVH*BEVW) // 32768
#define BCAP 16
#define EXT 20.0f
#define BN_S 0.99999500003749937f

typedef short bf16x8 __attribute__((ext_vector_type(8)));
typedef float f32x4 __attribute__((ext_vector_type(4)));

__device__ __forceinline__ float gelu(float x) {
    return 0.5f * x * (1.0f + erff(x * 0.70710678118654752f));
}

__device__ __forceinline__ unsigned short f2bf(float x) {
    union { float f; unsigned u; } v; v.f = x;
    unsigned r = v.u + 0x7FFFu + ((v.u >> 16) & 1u);
    return (unsigned short)(r >> 16);
}

// bf16 atomic add via 32-bit CAS (cold paths only)
__device__ void atomicAddBf16(unsigned short* addr, float val) {
    unsigned* base = (unsigned*)((size_t)addr & ~(size_t)3);
    bool hi = ((size_t)addr & 2) != 0;
    unsigned old = *base, assumed;
    do {
        assumed = old;
        unsigned short cur = hi ? (unsigned short)(assumed >> 16)
                                : (unsigned short)(assumed & 0xFFFF);
        union { unsigned u; float f; } vv; vv.u = ((unsigned)cur) << 16;
        unsigned short nb = f2bf(vv.f + val);
        unsigned newv = hi ? ((assumed & 0x0000FFFFu) | ((unsigned)nb << 16))
                           : ((assumed & 0xFFFF0000u) | (unsigned)nb);
        old = atomicCAS(base, assumed, newv);
    } while (old != assumed);
}

// ---------------- combined weight prep + count/ovf zeroing ----------------
#define WF1_N (9*4*8*64*8)
#define WFP_N (2*8*64*8)
#define WFC1_N (9*2*4*64*8)
__global__ void k_wprep_all(const float* __restrict__ br_w1, const float* __restrict__ br_w2,
                            const float* __restrict__ fp_w, const float* __restrict__ dh_w1,
                            unsigned short* __restrict__ wf1, unsigned short* __restrict__ wf2,
                            unsigned short* __restrict__ wfp, unsigned short* __restrict__ wfc1,
                            int* __restrict__ count, int* __restrict__ ovf_n) {
    int gi = blockIdx.x * 256 + threadIdx.x;
    if (gi < NCELL) count[gi] = 0;
    if (gi == 0) *ovf_n = 0;

    int i = gi;
    if (i < 2 * WF1_N) {
        const float* w = (i < WF1_N) ? br_w1 : br_w2;
        unsigned short* wf = (i < WF1_N) ? wf1 : wf2;
        int j = (i < WF1_N) ? i : i - WF1_N;
        int e     = j & 7;
        int lane  = (j >> 3) & 63;
        int ntile = (j >> 9) & 7;
        int kstep = (j >> 12) & 3;
        int kpos  = j >> 14;
        int co = ntile * 16 + (lane & 15);
        int ci = kstep * 32 + ((lane >> 4) << 3) + e;
        wf[j] = f2bf(w[((size_t)co * BEVC + ci) * 9 + kpos]);
        return;
    }
    i -= 2 * WF1_N;
    if (i < WFP_N) {
        int e     = i & 7;
        int lane  = (i >> 3) & 63;
        int ntile = (i >> 9) & 7;
        int kstep = (i >> 12) & 1;
        int co = ntile * 16 + (lane & 15);
        int ci = kstep * 32 + ((lane >> 4) << 3) + e;
        wfp[i] = f2bf(fp_w[(size_t)co * CIN + ci]);
        return;
    }
    i -= WFP_N;
    if (i < WFC1_N) {
        int e     = i & 7;
        int lane  = (i >> 3) & 63;
        int ntile = (i >> 9) & 3;
        int kstep = (i >> 11) & 1;
        int kpos  = i >> 12;
        int co = ntile * 16 + (lane & 15);
        int ci = kstep * 32 + ((lane >> 4) << 3) + e;
        wfc1[i] = f2bf(dh_w1[((size_t)co * CIN + ci) * 9 + kpos]);
    }
}

// ---------------- Kernel 1: fused conv1(MFMA) + depth head + softmax + fp(MFMA) ----------------
// block 256 (4 waves). Tile 16x * 4y. grid (4, 8, BV). NCHW in; dp + fp out.
#define C1_HW 18
#define C1_HP (C1_HW*6)   // 108 halo pixels
__global__ void k_conv1dfp(const float* __restrict__ fm, const unsigned short* __restrict__ wfrag,
                           const float* __restrict__ bias, const float* __restrict__ w2,
                           const float* __restrict__ b2, const unsigned short* __restrict__ wfp,
                           const float* __restrict__ fp_b,
                           float* __restrict__ dp, float* __restrict__ fpb) {
    __shared__ float hbuf[64 * 65];        // phase A: als halo (char alias); phase B: h tile
    __shared__ float wl2[ND * 65];
    __shared__ float bl2[ND];
    char* als = (char*)hbuf;

    int x0 = blockIdx.x * 16;
    int y0 = blockIdx.y * 4;
    int bv = blockIdx.z;
    const float* fmb = fm + (size_t)bv * CIN * NPIX;

    for (int i = threadIdx.x; i < ND * CIN; i += 256) {
        int d = i >> 6, ci = i & 63;
        wl2[d * 65 + ci] = w2[i];
    }
    if (threadIdx.x < ND) bl2[threadIdx.x] = b2[threadIdx.x];

    for (int i = threadIdx.x; i < C1_HP * 8; i += 256) {
        int pix = i >> 3, oct = i & 7;
        int r = pix / C1_HW, c = pix % C1_HW;
        int gy = y0 + r - 1, gx = x0 + c - 1;
        int4 w4 = {0, 0, 0, 0};
        if ((unsigned)gy < (unsigned)HF && (unsigned)gx < (unsigned)WF) {
            const float* p = fmb + (size_t)(oct * 8) * NPIX + gy * WF + gx;
            unsigned short b8[8];
            #pragma unroll
            for (int j = 0; j < 8; j++) b8[j] = f2bf(p[(size_t)j * NPIX]);
            w4.x = b8[0] | ((int)b8[1] << 16);
            w4.y = b8[2] | ((int)b8[3] << 16);
            w4.z = b8[4] | ((int)b8[5] << 16);
            w4.w = b8[6] | ((int)b8[7] << 16);
        }
        *(int4*)(als + pix * 128 + ((oct * 16) ^ ((pix & 7) << 4))) = w4;
    }
    __syncthreads();

    int wave = threadIdx.x >> 6;
    int lane = threadIdx.x & 63;
    int xx   = lane & 15;
    int kgrp = lane >> 4;

    const bf16x8* wv = (const bf16x8*)wfrag;
    float bi = bias[wave * 16 + xx];
    f32x4 acc[4];
    #pragma unroll
    for (int m = 0; m < 4; m++) acc[m] = (f32x4){bi, bi, bi, bi};

    for (int kpos = 0; kpos < 9; kpos++) {
        int dy = kpos / 3, dx = kpos % 3;
        #pragma unroll
        for (int kstep = 0; kstep < 2; kstep++) {
            bf16x8 b = wv[((kpos * 2 + kstep) * 4 + wave) * 64 + lane];
            #pragma unroll
            for (int m = 0; m < 4; m++) {
                int pix = (m + dy) * C1_HW + xx + dx;
                bf16x8 a = *(const bf16x8*)(als + pix * 128 +
                                            ((kstep * 64 + kgrp * 16) ^ ((pix & 7) << 4)));
                acc[m] = __builtin_amdgcn_mfma_f32_16x16x32_bf16(a, b, acc[m], 0, 0, 0);
            }
        }
    }

    // ---- fused fp: same halo LDS rows are the A-fragments. wave = y-row m. ----
    {
        const bf16x8* wvp = (const bf16x8*)wfp;
        int hpix = (wave + 1) * C1_HW + xx + 1;
        bf16x8 fa0 = *(const bf16x8*)(als + hpix * 128 +
                                      ((       kgrp * 16) ^ ((hpix & 7) << 4)));
        bf16x8 fa1 = *(const bf16x8*)(als + hpix * 128 +
                                      ((64 +   kgrp * 16) ^ ((hpix & 7) << 4)));
        #pragma unroll
        for (int n = 0; n < 8; n++) {
            float fb = fp_b[n * 16 + xx];
            f32x4 facc = (f32x4){fb, fb, fb, fb};
            facc = __builtin_amdgcn_mfma_f32_16x16x32_bf16(fa0, wvp[(0 * 8 + n) * 64 + lane], facc, 0, 0, 0);
            facc = __builtin_amdgcn_mfma_f32_16x16x32_bf16(fa1, wvp[(1 * 8 + n) * 64 + lane], facc, 0, 0, 0);
            #pragma unroll
            for (int r = 0; r < 4; r++) {
                int gx = x0 + kgrp * 4 + r;
                if (gx < WF)
                    fpb[((size_t)bv * NPIX + (y0 + wave) * WF + gx) * BEVC + n * 16 + xx] =
                        gelu(facc[r] * BN_S);
            }
        }
    }
    __syncthreads();

    #pragma unroll
    for (int m = 0; m < 4; m++) {
        #pragma unroll
        for (int r = 0; r < 4; r++) {
            int pixel = m * 16 + kgrp * 4 + r;
            hbuf[pixel * 65 + wave * 16 + xx] = gelu(acc[m][r] * BN_S);
        }
    }
    __syncthreads();

    {
        int pixel = threadIdx.x >> 2;
        int part  = threadIdx.x & 3;
        int m = pixel >> 4, xcol = pixel & 15;
        int gy = y0 + m, gx = x0 + xcol;

        float hv[CIN];
        #pragma unroll
        for (int c4 = 0; c4 < CIN / 4; c4++) {
            float4 v = *(const float4*)&hbuf[pixel * 65 + c4 * 4];
            hv[c4 * 4 + 0] = v.x; hv[c4 * 4 + 1] = v.y;
            hv[c4 * 4 + 2] = v.z; hv[c4 * 4 + 3] = v.w;
        }
        float o[8];
        float mx = -1e30f;
        #pragma unroll
        for (int dd = 0; dd < 8; dd++) {
            int d = part * 8 + dd;
            float a = bl2[d];
            #pragma unroll
            for (int ci = 0; ci < CIN; ci++) a += wl2[d * 65 + ci] * hv[ci];
            o[dd] = a;
            mx = fmaxf(mx, a);
        }
        mx = fmaxf(mx, __shfl_xor(mx, 1));
        mx = fmaxf(mx, __shfl_xor(mx, 2));
        float s = 0.f;
        #pragma unroll
        for (int dd = 0; dd < 8; dd++) { o[dd] = expf(o[dd] - mx); s += o[dd]; }
        s += __shfl_xor(s, 1);
        s += __shfl_xor(s, 2);
        float inv = 1.0f / s;
        if (gx < WF) {
            float* op = dp + ((size_t)bv * NPIX + gy * WF + gx) * ND + part * 8;
            float4 v0 = {o[0] * inv, o[1] * inv, o[2] * inv, o[3] * inv};
            float4 v1 = {o[4] * inv, o[5] * inv, o[6] * inv, o[7] * inv};
            ((float4*)op)[0] = v0;
            ((float4*)op)[1] = v1;
        }
    }
}

// ---------------- geometry helper ----------------
struct Geo {
    float i00,i01,i02,i10,i11,i12,i20,i21,i22;
    float R00,R01,R02,t0,R10,R11,R12,t1;
};
__device__ __forceinline__ Geo load_geo(const float* Km, const float* Tm, int bv) {
    Geo G;
    const float* Kp = Km + bv * 9;
    float a = Kp[0], bb = Kp[1], cc = Kp[2];
    float d = Kp[3], e  = Kp[4], f  = Kp[5];
    float g = Kp[6], hh = Kp[7], ii = Kp[8];
    float A  = e * ii - f * hh;
    float Bm = -(d * ii - f * g);
    float Cm = d * hh - e * g;
    float det = a * A + bb * Bm + cc * Cm;
    float invd = 1.0f / det;
    G.i00 = A * invd;  G.i01 = -(bb * ii - cc * hh) * invd; G.i02 = (bb * f - cc * e) * invd;
    G.i10 = Bm * invd; G.i11 = (a * ii - cc * g) * invd;    G.i12 = -(a * f - cc * d) * invd;
    G.i20 = Cm * invd; G.i21 = -(a * hh - bb * g) * invd;   G.i22 = (a * e - bb * d) * invd;
    const float* Tp = Tm + bv * 16;
    G.R00 = Tp[0]; G.R01 = Tp[1]; G.R02 = Tp[2]; G.t0 = Tp[3];
    G.R10 = Tp[4]; G.R11 = Tp[5]; G.R12 = Tp[6]; G.t1 = Tp[7];
    return G;
}
__device__ __forceinline__ int geo_cell(const Geo& G, int px, int py, float dep) {
    float fx = (float)px, fy = (float)py;
    float r0 = G.i00 * fx + G.i01 * fy + G.i02;
    float r1 = G.i10 * fx + G.i11 * fy + G.i12;
    float r2 = G.i20 * fx + G.i21 * fy + G.i22;
    float xe = G.R00 * (r0 * dep) + G.R01 * (r1 * dep) + G.R02 * (r2 * dep) + G.t0;
    float ye = G.R10 * (r0 * dep) + G.R11 * (r1 * dep) + G.R12 * (r2 * dep) + G.t1;
    int col = (int)((xe + EXT) / (2.0f * EXT) * (float)(BEVW - 1));
    int row = (int)((ye + EXT) / (2.0f * EXT) * (float)(BEVH - 1));
    return (col >= 0 && col < BEVW && row >= 0 && row < BEVH) ? row * BEVW + col : -1;
}

// ---------------- Kernel 4a: per-column py-pre-reduction + bucket append ----------------
__global__ void k_prered(const float* __restrict__ fp, const float* __restrict__ dp,
                         const float* __restrict__ Km, const float* __restrict__ Tm,
                         const float* __restrict__ trust, const float* __restrict__ depths,
                         float* __restrict__ M, int* __restrict__ cellidx,
                         int* __restrict__ count, int* __restrict__ bucket,
                         int* __restrict__ ovf, int* __restrict__ ovf_n) {
    __shared__ float fpl[HF * BEVC];
    __shared__ float dpl[HF * ND];
    __shared__ int   celll[ND * HF];
    __shared__ int   uni[ND];

    int col = blockIdx.x;
    int bv = col / WF, px = col % WF;
    int b  = bv / NV;
    float tw = trust[bv];

    for (int i = threadIdx.x; i < HF * (BEVC / 4); i += 256) {
        int py = i >> 5, c4 = i & 31;
        float4 v = ((const float4*)(fp + ((size_t)bv * NPIX + py * WF + px) * BEVC))[c4];
        v.x *= tw; v.y *= tw; v.z *= tw; v.w *= tw;
        ((float4*)fpl)[py * 32 + c4] = v;
    }
    for (int i = threadIdx.x; i < HF * (ND / 4); i += 256) {
        int py = i >> 3, d4 = i & 7;
        ((float4*)dpl)[py * 8 + d4] =
            ((const float4*)(dp + ((size_t)bv * NPIX + py * WF + px) * ND))[d4];
    }

    Geo G = load_geo(Km, Tm, bv);
    for (int q = threadIdx.x; q < ND * HF; q += 256) {
        int di = q >> 5, py = q & 31;
        celll[q] = geo_cell(G, px, py, depths[di]);
    }
    __syncthreads();

    if (threadIdx.x < ND) {
        int di = threadIdx.x;
        int c0 = celll[di * HF];
        bool u = true;
        for (int py = 1; py < HF; py++) u &= (celll[di * HF + py] == c0);
        uni[di] = u ? c0 : -2;
    }
    __syncthreads();

    int c = threadIdx.x & 127, dg = threadIdx.x >> 7;
    float acc[16];
    #pragma unroll
    for (int k = 0; k < 16; k++) acc[k] = 0.f;
    for (int py = 0; py < HF; py++) {
        float fv = fpl[py * BEVC + c];
        #pragma unroll
        for (int k = 0; k < 16; k++)
            acc[k] += fv * dpl[py * ND + dg * 16 + k];
    }
    #pragma unroll
    for (int k = 0; k < 16; k++)
        M[((size_t)col * ND + dg * 16 + k) * BEVC + c] = acc[k];

    if (threadIdx.x < ND) {
        int u = uni[threadIdx.x];
        int id = (u >= 0) ? (b * (BEVH * BEVW) + u) : u;
        int item = col * ND + threadIdx.x;
        cellidx[item] = id;
        if (id >= 0) {
            int slot = atomicAdd(&count[id], 1);
            if (slot < BCAP) bucket[id * BCAP + slot] = item;
            else             ovf[atomicAdd(ovf_n, 1)] = item;
        }
    }
}

// ---------------- Kernel 4e: gather from buckets -> bf16 bev ----------------
__global__ void k_gather(const float* __restrict__ M, const int* __restrict__ count,
                         const int* __restrict__ bucket, unsigned short* __restrict__ bev) {
    int cell = blockIdx.x;
    int n = count[cell];
    if (n > BCAP) n = BCAP;
    int c = threadIdx.x;
    float acc = 0.f;
    for (int j = 0; j < n; j++) {
        int it = bucket[cell * BCAP + j];   // wave-uniform scalar load
        acc += M[(size_t)it * BEVC + c];
    }
    bev[(size_t)cell * BEVC + c] = f2bf(acc);
}

// ---------------- Kernel 4o: apply overflow items (normally no-op) ----------------
__global__ void k_ovf(const float* __restrict__ M, const int* __restrict__ cellidx,
                      const int* __restrict__ ovf, const int* __restrict__ ovf_n,
                      unsigned short* __restrict__ bev) {
    int no = *ovf_n;
    int c = threadIdx.x;
    for (int i = blockIdx.x; i < no; i += gridDim.x) {
        int it = ovf[i];
        int cell = cellidx[it];
        atomicAddBf16(&bev[(size_t)cell * BEVC + c], M[(size_t)it * BEVC + c]);
    }
}

// ---------------- Kernel 4f: generic fallback for non-uniform columns (normally no-op) ----
__global__ void k_fallback(const float* __restrict__ fp, const float* __restrict__ dp,
                           const float* __restrict__ Km, const float* __restrict__ Tm,
                           const float* __restrict__ trust, const float* __restrict__ depths,
                           const int* __restrict__ cellidx, unsigned short* __restrict__ bev) {
    int col = blockIdx.x;
    bool any = false;
    for (int di = 0; di < ND; di++) any |= (cellidx[col * ND + di] == -2);
    if (!any) return;

    int bv = col / WF, px = col % WF;
    int b  = bv / NV;
    float tw = trust[bv];
    Geo G = load_geo(Km, Tm, bv);
    int c = threadIdx.x;
    unsigned short* bevb = bev + (size_t)b * BEVH * BEVW * BEVC;
    for (int di = 0; di < ND; di++) {
        if (cellidx[col * ND + di] != -2) continue;
        float dep = depths[di];
        for (int py = 0; py < HF; py++) {
            int cell = geo_cell(G, px, py, dep);
            if (cell >= 0) {
                float v = fp[((size_t)bv * NPIX + py * WF + px) * BEVC + c] * tw *
                          dp[((size_t)bv * NPIX + py * WF + px) * ND + di];
                atomicAddBf16(&bevb[(size_t)cell * BEVC + c], v);
            }
        }
    }
}

// ---------------- Kernel 5/6: 3x3 conv 128->128 via MFMA bf16, bf16 in ----------------
// TO_MODE: 1 = bf16 NHWC, 2 = fp32 NCHW (fused transpose). XCD-chunked grid.
// Ring-buffer weight prefetch (depth 4).
#define TX2 16
#define TY2 4
#define HALO_W 18
#define HP (HALO_W*6)   // 108

__device__ __forceinline__ int swz(int pix, int off) {
    return pix * 256 + (off ^ ((pix & 7) << 4));
}

template<int TO_MODE>
__global__ __launch_bounds__(256, 2)
void k_bevconv(const unsigned short* __restrict__ in_,
               const unsigned short* __restrict__ wfrag,
               const float* __restrict__ bias, void* __restrict__ out_) {
    __shared__ char ldsb[HP * 256];   // phase A: halo; phase B: output tile
    int bid = blockIdx.x;
    int id = (bid & 7) * 64 + (bid >> 3);
    int x0 = (id & 7) * TX2;
    int y0 = ((id >> 3) & 31) * TY2;
    int b  = id >> 8;

    for (int t = threadIdx.x; t < HP * 16; t += 256) {
        int pix = t >> 4, oct = t & 15;
        int r = pix / HALO_W, c = pix % HALO_W;
        int gy = y0 + r - 1, gx = x0 + c - 1;
        int4 w4 = {0, 0, 0, 0};
        if ((unsigned)gy < (unsigned)BEVH && (unsigned)gx < (unsigned)BEVW)
            w4 = *(const int4*)(in_ + ((size_t)(b * BEVH + gy) * BEVW + gx) * BEVC + oct * 8);
        *(int4*)(ldsb + swz(pix, oct * 16)) = w4;
    }

    int wave = threadIdx.x >> 6;
    int lane = threadIdx.x & 63;
    int xx   = lane & 15;
    int kgrp = lane >> 4;

    const bf16x8* wv = (const bf16x8*)wfrag;
    int wbase = wave * 2;

    bf16x8 wq[4][2];
    #pragma unroll
    for (int p = 0; p < 4; p++) {
        wq[p][0] = wv[(p * 8 + wbase + 0) * 64 + lane];
        wq[p][1] = wv[(p * 8 + wbase + 1) * 64 + lane];
    }

    f32x4 acc[TY2][2];
    {
        float b0 = bias[wave * 32 + xx];
        float b1 = bias[wave * 32 + 16 + xx];
        #pragma unroll
        for (int m = 0; m < TY2; m++) {
            acc[m][0] = (f32x4){b0, b0, b0, b0};
            acc[m][1] = (f32x4){b1, b1, b1, b1};
        }
    }
    __syncthreads();

    #pragma unroll
    for (int i = 0; i < 36; i++) {           // i = kpos*4 + kstep
        const int kpos = i >> 2, kstep = i & 3;
        const int dy = kpos / 3, dx = kpos % 3;
        bf16x8 b0 = wq[i & 3][0];
        bf16x8 b1 = wq[i & 3][1];
        if (i + 4 < 36) {
            wq[i & 3][0] = wv[((i + 4) * 8 + wbase + 0) * 64 + lane];
            wq[i & 3][1] = wv[((i + 4) * 8 + wbase + 1) * 64 + lane];
        }
        #pragma unroll
        for (int m = 0; m < TY2; m++) {
            bf16x8 a = *(const bf16x8*)(ldsb + swz((m + dy) * HALO_W + xx + dx,
                                                   kstep * 64 + kgrp * 16));
            acc[m][0] = __builtin_amdgcn_mfma_f32_16x16x32_bf16(a, b0, acc[m][0], 0, 0, 0);
            acc[m][1] = __builtin_amdgcn_mfma_f32_16x16x32_bf16(a, b1, acc[m][1], 0, 0, 0);
        }
    }
    __syncthreads();   // halo reads done; reuse LDS for output tile

    if (TO_MODE == 1) {
        unsigned short* hl = (unsigned short*)ldsb;  // [64][136] padded
        #pragma unroll
        for (int m = 0; m < TY2; m++)
            #pragma unroll
            for (int n = 0; n < 2; n++)
                #pragma unroll
                for (int r = 0; r < 4; r++) {
                    int pid = m * 16 + kgrp * 4 + r;
                    hl[pid * 136 + wave * 32 + n * 16 + xx] = f2bf(gelu(acc[m][n][r] * BN_S));
                }
        __syncthreads();
        for (int t = threadIdx.x; t < 1024; t += 256) {
            int pid = t >> 4, oct = t & 15;
            int gy = y0 + (pid >> 4), gx = x0 + (pid & 15);
            *(int4*)((unsigned short*)out_ + ((size_t)(b * BEVH + gy) * BEVW + gx) * BEVC + oct * 8) =
                *(int4*)(hl + pid * 136 + oct * 8);
        }
    } else {
        float* fl = (float*)ldsb;   // [64][66] floats
        #pragma unroll
        for (int half = 0; half < 2; half++) {
            if (half == 1) __syncthreads();
            if ((wave >> 1) == half) {
                #pragma unroll
                for (int m = 0; m < TY2; m++)
                    #pragma unroll
                    for (int n = 0; n < 2; n++)
                        #pragma unroll
                        for (int r = 0; r < 4; r++) {
                            int pid = m * 16 + kgrp * 4 + r;
                            fl[pid * 66 + (wave & 1) * 32 + n * 16 + xx] =
                                gelu(acc[m][n][r] * BN_S);
                        }
            }
            __syncthreads();
            for (int t = threadIdx.x; t < 1024; t += 256) {
                int l4 = t & 3, gyl = (t >> 2) & 3, col = t >> 4;
                int co = half * 64 + col;
                int gy = y0 + gyl;
                float4 v;
                v.x = fl[(gyl * 16 + l4 * 4 + 0) * 66 + col];
                v.y = fl[(gyl * 16 + l4 * 4 + 1) * 66 + col];
                v.z = fl[(gyl * 16 + l4 * 4 + 2) * 66 + col];
                v.w = fl[(gyl * 16 + l4 * 4 + 3) * 66 + col];
                *(float4*)((float*)out_ + (((size_t)b * BEVC + co) * BEVH + gy) * BEVW +
                           x0 + l4 * 4) = v;
            }
        }
    }
}

extern "C" void kernel_launch(void* const* d_in, const int* in_sizes, int n_in,
                              void* d_out, int out_size, void* d_ws, size_t ws_size,
                              hipStream_t stream) {
    const float* feat_maps = (const float*)d_in[0];
    const float* Km        = (const float*)d_in[1];
    const float* Tm        = (const float*)d_in[2];
    const float* trust     = (const float*)d_in[3];
    const float* depths    = (const float*)d_in[4];
    const float* dh_w1     = (const float*)d_in[5];
    const float* dh_b1     = (const float*)d_in[6];
    const float* dh_w2     = (const float*)d_in[7];
    const float* dh_b2     = (const float*)d_in[8];
    const float* fp_w      = (const float*)d_in[9];
    const float* fp_b      = (const float*)d_in[10];
    const float* br_w1     = (const float*)d_in[11];
    const float* br_b1     = (const float*)d_in[12];
    const float* br_w2     = (const float*)d_in[13];
    const float* br_b2     = (const float*)d_in[14];
    float* out = (float*)d_out;

    float* ws  = (float*)d_ws;
    float* dpb = ws;                                     // 12*1792*32 f
    float* fpb = dpb + (size_t)BV * NPIX * ND;           // 12*1792*128 f
    float* Mb  = fpb + (size_t)BV * NPIX * BEVC;         // 21504*128 f
    unsigned short* bevb = (unsigned short*)(Mb + (size_t)NITEM * BEVC); // NCELL*128 bf16
    unsigned short* h2b  = bevb + (size_t)NCELL * BEVC;                  // NCELL*128 bf16
    unsigned short* wf1  = h2b + (size_t)NCELL * BEVC;
    unsigned short* wf2  = wf1 + (size_t)WF1_N;
    unsigned short* wfp  = wf2 + (size_t)WF1_N;
    unsigned short* wfc1 = wfp + WFP_N;
    int* cellidx  = (int*)(wfc1 + WFC1_N);  // NITEM
    int* count    = cellidx + NITEM;        // NCELL
    int* bucket   = count + NCELL;          // NCELL*BCAP
    int* ovf      = bucket + NCELL * BCAP;  // NITEM
    int* ovf_n    = ovf + NITEM;            // 1

    // combined weight prep + count/ovf zeroing
    {
        int total = 2 * WF1_N + WFP_N + WFC1_N;
        k_wprep_all<<<dim3((total + 255) / 256), dim3(256), 0, stream>>>(
            br_w1, br_w2, fp_w, dh_w1, wf1, wf2, wfp, wfc1, count, ovf_n);
    }

    // fused conv1 + depth head + softmax + fp
    k_conv1dfp<<<dim3(4, HF / 4, BV), dim3(256), 0, stream>>>(
        feat_maps, wfc1, dh_b1, dh_w2, dh_b2, wfp, fp_b, dpb, fpb);

    // --- scatter via bucket-append + gather (no fp32 atomics, no scan) ---
    k_prered<<<dim3(NCOL), dim3(256), 0, stream>>>(fpb, dpb, Km, Tm, trust, depths,
                                                   Mb, cellidx, count, bucket, ovf, ovf_n);
    k_gather<<<dim3(NCELL), dim3(BEVC), 0, stream>>>(Mb, count, bucket, bevb);
    k_ovf<<<dim3(64), dim3(BEVC), 0, stream>>>(Mb, cellidx, ovf, ovf_n, bevb);
    k_fallback<<<dim3(NCOL), dim3(BEVC), 0, stream>>>(fpb, dpb, Km, Tm, trust, depths,
                                                      cellidx, bevb);

    // BEV refinement convs (MFMA, bf16 in): -> bf16 NHWC, then -> fp32 NCHW (fused transpose)
    k_bevconv<1><<<dim3(512), dim3(256), 0, stream>>>(bevb, wf1, br_b1, h2b);
    k_bevconv<2><<<dim3(512), dim3(256), 0, stream>>>(h2b, wf2, br_b2, out);
}